// Round 11
// baseline (557.904 us; speedup 1.0000x reference)
//
#include <hip/hip_runtime.h>
#include <hip/hip_bf16.h>
#include <math.h>

#define N_NODES 40000
#define N_EDGES 640000
#define N_GRAPH 64
#define HEADS 4
#define CHAN 64
#define HC 256          // HEADS*CHAN
#define NHID 1024
#define NOUT 768
#define E_TOT (N_EDGES + N_NODES)
#define SCAN_NB ((N_NODES + 255) / 256)   // 157

typedef __attribute__((ext_vector_type(8))) short bf16x8;
typedef __attribute__((ext_vector_type(4))) float f32x4;

__device__ inline float bflo(unsigned u) { return __uint_as_float(u << 16); }
__device__ inline float bfhi(unsigned u) { return __uint_as_float(u & 0xffff0000u); }

__device__ inline unsigned bfbits(float f) {
    __hip_bfloat16 b = __float2bfloat16(f);
    return (unsigned)*reinterpret_cast<unsigned short*>(&b);
}
__device__ inline unsigned pk2bf(float lo, float hi) {
    return bfbits(lo) | (bfbits(hi) << 16);
}

// ---------------- weight transpose (all 3 layers, one launch) ----------------

__global__ void conv_wt3_kernel(const float* __restrict__ W1, const float* __restrict__ W2,
                                const float* __restrict__ W3, __hip_bfloat16* __restrict__ T1,
                                __hip_bfloat16* __restrict__ T2, __hip_bfloat16* __restrict__ T3) {
    const float* W = (blockIdx.y == 0) ? W1 : (blockIdx.y == 1) ? W2 : W3;
    __hip_bfloat16* T = (blockIdx.y == 0) ? T1 : (blockIdx.y == 1) ? T2 : T3;
    int k = blockIdx.x, n = threadIdx.x;
    T[(size_t)n * 256 + k] = __float2bfloat16(W[(size_t)k * 256 + n]);
}

// ---------------- CSR build ----------------

__global__ void count_deg_kernel(const int* __restrict__ ei, int* __restrict__ deg) {
    int i = blockIdx.x * blockDim.x + threadIdx.x;
    if (i >= E_TOT) return;
    int dst = (i < N_EDGES) ? ei[N_EDGES + i] : (i - N_EDGES);
    atomicAdd(&deg[dst], 1);
}

__global__ __launch_bounds__(256)
void scan_p1_kernel(const int* __restrict__ deg, int* __restrict__ bsum) {
    const int b = blockIdx.x, t = threadIdx.x;
    const int i = b * 256 + t;
    int v = (i < N_NODES) ? deg[i] : 0;
    #pragma unroll
    for (int off = 1; off < 64; off <<= 1) v += __shfl_xor(v, off, 64);
    __shared__ int ws[4];
    if ((t & 63) == 0) ws[t >> 6] = v;
    __syncthreads();
    if (t == 0) bsum[b] = ws[0] + ws[1] + ws[2] + ws[3];
}

__global__ __launch_bounds__(256)
void scan_p2_kernel(int* __restrict__ bsum) {     // single block; SCAN_NB <= 256
    __shared__ int s[256];
    const int t = threadIdx.x;
    int v = (t < SCAN_NB) ? bsum[t] : 0;
    s[t] = v;
    __syncthreads();
    #pragma unroll
    for (int off = 1; off < 256; off <<= 1) {
        int x = (t >= off) ? s[t - off] : 0;
        __syncthreads();
        s[t] += x;
        __syncthreads();
    }
    if (t < SCAN_NB) bsum[t] = s[t] - v;          // exclusive block offset
}

__global__ __launch_bounds__(256)
void scan_p3_kernel(const int* __restrict__ deg, const int* __restrict__ bsum,
                    int* __restrict__ rowptr) {
    __shared__ int s[256];
    const int b = blockIdx.x, t = threadIdx.x;
    const int i = b * 256 + t;
    int v = (i < N_NODES) ? deg[i] : 0;
    s[t] = v;
    __syncthreads();
    #pragma unroll
    for (int off = 1; off < 256; off <<= 1) {
        int x = (t >= off) ? s[t - off] : 0;
        __syncthreads();
        s[t] += x;
        __syncthreads();
    }
    if (i < N_NODES) rowptr[i] = bsum[b] + s[t] - v;
    if (i == 0) rowptr[N_NODES] = E_TOT;          // total is static
}

__global__ void fill_csr_kernel(const int* __restrict__ ei, const int* __restrict__ rowptr,
                                int* __restrict__ cursor, int* __restrict__ csr_src) {
    int i = blockIdx.x * blockDim.x + threadIdx.x;
    if (i >= E_TOT) return;
    int src, dst;
    if (i < N_EDGES) { src = ei[i]; dst = ei[N_EDGES + i]; }
    else             { src = dst = i - N_EDGES; }
    int pos = atomicAdd(&cursor[dst], 1);
    csr_src[rowptr[dst] + pos] = src;
}

// ---------------- bf16 MFMA GEMM: W-resident-in-LDS, B-frags in registers ----------------
// grid (125, 2): blockIdx.y = column half (2 heads). Block = 8 waves (512 thr).
// Stage 64KB W-half into LDS ONCE (XOR-swizzled), one barrier; each wave pulls its head's
// B fragments into 128 persistent VGPRs; then waves independently stream 16-row A tiles.

template<int CAST>
__global__ __launch_bounds__(512, 2)
void gemm_mfma_kernel(const void* __restrict__ Ain, const __hip_bfloat16* __restrict__ Wt,
                      __hip_bfloat16* __restrict__ C,
                      const float* __restrict__ a_s, const float* __restrict__ a_d,
                      float* __restrict__ asrc, float* __restrict__ adst) {
    __shared__ ushort Wl[128 * 256];    // 64 KB, 16B chunks XOR-swizzled: slot = q ^ (col&7)

    const int tid = threadIdx.x;
    const int lane = tid & 63;
    const int l15 = lane & 15, lq = lane >> 4;
    const int w = tid >> 6;
    const int hsel = w >> 2;
    const int stripe = w & 3;
    const int head = blockIdx.y * 2 + hsel;
    const int row_base = blockIdx.x * 320;

    // ---- stage W column-half (128 cols x 256 k) into LDS, swizzled
    {
        const int col = tid >> 2;                 // 0..127
        const char* Wb = (const char*)(Wt + (size_t)(blockIdx.y * 128 + col) * 256);
        #pragma unroll
        for (int j = 0; j < 8; j++) {
            int q = (tid & 3) * 8 + j;            // 16B chunk 0..31
            uint4 v = *reinterpret_cast<const uint4*>(Wb + q * 16);
            *reinterpret_cast<uint4*>(&Wl[col * 256 + ((q ^ (col & 7)) * 8)]) = v;
        }
    }
    __syncthreads();

    // ---- this wave's B fragments -> persistent registers (128 VGPRs)
    bf16x8 b[8][4];
    #pragma unroll
    for (int kt = 0; kt < 8; kt++)
        #pragma unroll
        for (int n = 0; n < 4; n++) {
            int cl = hsel * 64 + n * 16 + l15;
            int q = kt * 4 + lq;
            b[kt][n] = *reinterpret_cast<const bf16x8*>(&Wl[cl * 256 + ((q ^ (cl & 7)) * 8)]);
        }

    float was[4], wad[4];
    #pragma unroll
    for (int n = 0; n < 4; n++) {
        was[n] = a_s[head * 64 + n * 16 + l15];
        wad[n] = a_d[head * 64 + n * 16 + l15];
    }

    auto loadA = [&](int T, bf16x8* a) {
        const int row = row_base + T * 16 + l15;
        if (CAST) {
            const float* Af = (const float*)Ain;
            #pragma unroll
            for (int kt = 0; kt < 8; kt++) {
                float4 u0 = *reinterpret_cast<const float4*>(&Af[(size_t)row * 256 + kt * 32 + lq * 8]);
                float4 u1 = *reinterpret_cast<const float4*>(&Af[(size_t)row * 256 + kt * 32 + lq * 8 + 4]);
                uint4 uv = make_uint4(pk2bf(u0.x, u0.y), pk2bf(u0.z, u0.w),
                                      pk2bf(u1.x, u1.y), pk2bf(u1.z, u1.w));
                a[kt] = *reinterpret_cast<bf16x8*>(&uv);
            }
        } else {
            const __hip_bfloat16* Ab = (const __hip_bfloat16*)Ain;
            #pragma unroll
            for (int kt = 0; kt < 8; kt++) {
                uint4 uv = *reinterpret_cast<const uint4*>(&Ab[(size_t)row * 256 + kt * 32 + lq * 8]);
                a[kt] = *reinterpret_cast<bf16x8*>(&uv);
            }
        }
    };

    bf16x8 aA[8], aB[8];
    loadA(stripe, aA);
    #pragma unroll
    for (int ti = 0; ti < 5; ti++) {
        const int T = stripe + ti * 4;
        if (ti < 4) loadA(T + 4, aB);             // prefetch next tile under the MFMAs
        f32x4 acc[4];
        #pragma unroll
        for (int n = 0; n < 4; n++) acc[n] = (f32x4){0.f, 0.f, 0.f, 0.f};
        #pragma unroll
        for (int kt = 0; kt < 8; kt++)
            #pragma unroll
            for (int n = 0; n < 4; n++)
                acc[n] = __builtin_amdgcn_mfma_f32_16x16x32_bf16(aA[kt], b[kt][n], acc[n], 0, 0, 0);

        #pragma unroll
        for (int reg = 0; reg < 4; reg++) {
            float ps = 0.f, pd = 0.f;
            #pragma unroll
            for (int n = 0; n < 4; n++) {
                float v = acc[n][reg];
                ps = fmaf(v, was[n], ps);
                pd = fmaf(v, wad[n], pd);
            }
            #pragma unroll
            for (int off = 1; off < 16; off <<= 1) {
                ps += __shfl_xor(ps, off, 16);
                pd += __shfl_xor(pd, off, 16);
            }
            const int row = row_base + T * 16 + lq * 4 + reg;
            if (l15 == 0) {
                asrc[row * 4 + head] = ps;
                adst[row * 4 + head] = pd;
            }
        }
        #pragma unroll
        for (int n = 0; n < 4; n++)
            #pragma unroll
            for (int reg = 0; reg < 4; reg++) {
                float v = acc[n][reg];
                float vp = __shfl_xor(v, 1, 16);   // partner column
                const int row = row_base + T * 16 + lq * 4 + reg;
                if (!(l15 & 1)) {
                    unsigned pk = pk2bf(v, vp);
                    *reinterpret_cast<unsigned*>(&C[(size_t)row * 256 + head * 64 + n * 16 + l15]) = pk;
                }
            }
        #pragma unroll
        for (int kk = 0; kk < 8; kk++) aA[kk] = aB[kk];
    }
}

// ---------------- fused edge-softmax + aggregation (max-free, wave-per-head) ----------------

#define ACHUNK 256

__global__ __launch_bounds__(256)
void gat_fused_agg(const __hip_bfloat16* __restrict__ h, const float* __restrict__ asrc,
                   const float* __restrict__ adst, const int* __restrict__ rowptr,
                   const int* __restrict__ csr_src, const float* __restrict__ bias,
                   __hip_bfloat16* __restrict__ out, int do_relu) {
    __shared__ int   s_src[ACHUNK];
    __shared__ float s_w[ACHUNK][5];    // pad 4->5: conflict-free phase-0 writes
    __shared__ float s_acc[8][HC];
    __shared__ float s_sum[4];

    const int n = blockIdx.x;
    const int t = threadIdx.x;
    const int lane = t & 63;
    const int wid = t >> 6;         // wave id == head in phase 0
    const int grp = t >> 5;         // phase-1 group (edge parity)
    const int gl  = t & 31;         // lane in group; channels gl*8..gl*8+7
    const int h3  = gl >> 3;        // head owning those channels
    const int start = rowptr[n];
    const int deg = rowptr[n + 1] - start;
    const float ad = adst[n * 4 + wid];

    float ssum = 0.f;
    float acc[8] = {0.f, 0.f, 0.f, 0.f, 0.f, 0.f, 0.f, 0.f};

    for (int c0 = 0; c0 < deg; c0 += ACHUNK) {
        const int cn = min(ACHUNK, deg - c0);
        if (c0) __syncthreads();
        for (int e = lane; e < cn; e += 64) {
            int src = csr_src[start + c0 + e];
            if (wid == 0) s_src[e] = src;
            float sc = asrc[src * 4 + wid] + ad;
            sc = (sc >= 0.f) ? sc : 0.2f * sc;   // leaky relu 0.2
            float w = __expf(sc);
            s_w[e][wid] = w;
            ssum += w;
        }
        __syncthreads();
        #pragma unroll 2
        for (int e = grp; e < cn; e += 8) {
            float w = s_w[e][h3];
            uint4 v = *reinterpret_cast<const uint4*>(&h[(size_t)s_src[e] * HC + gl * 8]);
            acc[0] = fmaf(w, bflo(v.x), acc[0]);
            acc[1] = fmaf(w, bfhi(v.x), acc[1]);
            acc[2] = fmaf(w, bflo(v.y), acc[2]);
            acc[3] = fmaf(w, bfhi(v.y), acc[3]);
            acc[4] = fmaf(w, bflo(v.z), acc[4]);
            acc[5] = fmaf(w, bfhi(v.z), acc[5]);
            acc[6] = fmaf(w, bflo(v.w), acc[6]);
            acc[7] = fmaf(w, bfhi(v.w), acc[7]);
        }
    }
    #pragma unroll
    for (int off = 1; off < 64; off <<= 1) ssum += __shfl_xor(ssum, off, 64);
    if (lane == 0) s_sum[wid] = ssum;
    *reinterpret_cast<float4*>(&s_acc[grp][gl * 8])     = make_float4(acc[0], acc[1], acc[2], acc[3]);
    *reinterpret_cast<float4*>(&s_acc[grp][gl * 8 + 4]) = make_float4(acc[4], acc[5], acc[6], acc[7]);
    __syncthreads();
    float tot = 0.f;
    #pragma unroll
    for (int g = 0; g < 8; g++) tot += s_acc[g][t];
    float r = tot / s_sum[t >> 6] + bias[t];
    if (do_relu) r = fmaxf(r, 0.f);
    out[(size_t)n * HC + t] = __float2bfloat16(r);
}

// ---------------- pooling (one block per graph) -> per-graph MEAN ----------------

__global__ __launch_bounds__(256)
void pool_kernel(const __hip_bfloat16* __restrict__ h, const int* __restrict__ batch,
                 float* __restrict__ pooled_mean) {
    __shared__ float s_acc[8][HC];
    const int g = blockIdx.x;
    const int t = threadIdx.x;
    const int grp = t >> 5;
    const int gl  = t & 31;
    int lo = 0, hi = N_NODES;
    while (lo < hi) { int mid = (lo + hi) >> 1; if (batch[mid] < g) lo = mid + 1; else hi = mid; }
    const int start = lo;
    lo = 0; hi = N_NODES;
    while (lo < hi) { int mid = (lo + hi) >> 1; if (batch[mid] < g + 1) lo = mid + 1; else hi = mid; }
    const int end = lo;

    float acc[8] = {0.f, 0.f, 0.f, 0.f, 0.f, 0.f, 0.f, 0.f};
    for (int n = start + grp; n < end; n += 8) {
        uint4 v = *reinterpret_cast<const uint4*>(&h[(size_t)n * HC + gl * 8]);
        acc[0] += bflo(v.x); acc[1] += bfhi(v.x);
        acc[2] += bflo(v.y); acc[3] += bfhi(v.y);
        acc[4] += bflo(v.z); acc[5] += bfhi(v.z);
        acc[6] += bflo(v.w); acc[7] += bfhi(v.w);
    }
    #pragma unroll
    for (int j = 0; j < 8; j++) s_acc[grp][gl * 8 + j] = acc[j];
    __syncthreads();
    float tot = 0.f;
    #pragma unroll
    for (int q = 0; q < 8; q++) tot += s_acc[q][t];
    const float inv = 1.0f / (float)max(end - start, 1);
    pooled_mean[g * HC + t] = tot * inv;
}

// ---------------- weight-stationary tiled MLP ----------------
// mlp1: hidden[64, 1024] = relu(mean[64,256] @ Wm1 + bm1). grid 16 x 64-col tiles.
// Each block: 4 K-chunks of 64; per thread col=t&63, 16 graphs (t>>6)*16.

__global__ __launch_bounds__(256)
void mlp1_tiled(const float* __restrict__ pm, const float* __restrict__ Wm1,
                const float* __restrict__ bm1, float* __restrict__ hidden) {
    __shared__ float Ps[64][65];
    __shared__ float Ws[64][65];
    const int t = threadIdx.x;
    const int colb = blockIdx.x * 64;
    const int col = t & 63;
    const int g0 = (t >> 6) * 16;
    float acc[16];
    #pragma unroll
    for (int i = 0; i < 16; i++) acc[i] = 0.f;

    for (int kc = 0; kc < 4; kc++) {
        if (kc) __syncthreads();
        #pragma unroll
        for (int j = 0; j < 16; j++) {
            int e = t + j * 256;                // 4096 elems
            int gg = e >> 6, kk = e & 63;
            Ps[gg][kk] = pm[gg * HC + kc * 64 + kk];
            Ws[gg][kk] = Wm1[(size_t)(kc * 64 + gg) * NHID + colb + kk];  // Ws[k][c]
        }
        __syncthreads();
        #pragma unroll 8
        for (int k = 0; k < 64; k++) {
            float wv = Ws[k][col];
            #pragma unroll
            for (int i = 0; i < 16; i++)
                acc[i] = fmaf(Ps[g0 + i][k], wv, acc[i]);
        }
    }
    float bv = bm1[colb + col];
    #pragma unroll
    for (int i = 0; i < 16; i++)
        hidden[(size_t)(g0 + i) * NHID + colb + col] = fmaxf(acc[i] + bv, 0.f);
}

// mlp2: out[64, 768] = hidden @ Wm2 + bm2. grid 12 x 64-col tiles, 8 K-chunks of 128.

__global__ __launch_bounds__(256)
void mlp2_tiled(const float* __restrict__ hidden, const float* __restrict__ Wm2,
                const float* __restrict__ bm2, float* __restrict__ out) {
    __shared__ float Hs[64][129];
    __shared__ float Ws[128][65];
    const int t = threadIdx.x;
    const int colb = blockIdx.x * 64;
    const int col = t & 63;
    const int g0 = (t >> 6) * 16;
    float acc[16];
    #pragma unroll
    for (int i = 0; i < 16; i++) acc[i] = 0.f;

    for (int kc = 0; kc < 8; kc++) {
        if (kc) __syncthreads();
        #pragma unroll
        for (int j = 0; j < 32; j++) {
            int e = t + j * 256;                // 8192 elems
            int gg = e >> 7, kk = e & 127;      // Hs[g][k]
            Hs[gg][kk] = hidden[(size_t)gg * NHID + kc * 128 + kk];
            int k2 = e >> 6, c2 = e & 63;       // Ws[k][c]
            Ws[k2][c2] = Wm2[(size_t)(kc * 128 + k2) * NOUT + colb + c2];
        }
        __syncthreads();
        #pragma unroll 8
        for (int k = 0; k < 128; k++) {
            float wv = Ws[k][col];
            #pragma unroll
            for (int i = 0; i < 16; i++)
                acc[i] = fmaf(Hs[g0 + i][k], wv, acc[i]);
        }
    }
    float bv = bm2[colb + col];
    #pragma unroll
    for (int i = 0; i < 16; i++)
        out[(size_t)(g0 + i) * NOUT + colb + col] = acc[i] + bv;
}

// ---------------- launch ----------------

extern "C" void kernel_launch(void* const* d_in, const int* in_sizes, int n_in,
                              void* d_out, int out_size, void* d_ws, size_t ws_size,
                              hipStream_t stream) {
    const float* x  = (const float*)d_in[0];
    const int* ei   = (const int*)d_in[1];
    const int* batch = (const int*)d_in[2];
    const float* W1 = (const float*)d_in[3];
    const float* as1 = (const float*)d_in[4];
    const float* ad1 = (const float*)d_in[5];
    const float* b1 = (const float*)d_in[6];
    const float* W2 = (const float*)d_in[7];
    const float* as2 = (const float*)d_in[8];
    const float* ad2 = (const float*)d_in[9];
    const float* b2 = (const float*)d_in[10];
    const float* W3 = (const float*)d_in[11];
    const float* as3 = (const float*)d_in[12];
    const float* ad3 = (const float*)d_in[13];
    const float* b3 = (const float*)d_in[14];
    const float* Wm1 = (const float*)d_in[15];
    const float* bm1 = (const float*)d_in[16];
    const float* Wm2 = (const float*)d_in[17];
    const float* bm2 = (const float*)d_in[18];
    float* out = (float*)d_out;

    char* base = (char*)d_ws;
    size_t off = 0;
    auto alloc = [&](size_t bytes) { char* p = base + off; off = (off + bytes + 255) & ~(size_t)255; return p; };
    __hip_bfloat16* hA   = (__hip_bfloat16*)alloc((size_t)N_NODES * 256 * 2);
    __hip_bfloat16* hB   = (__hip_bfloat16*)alloc((size_t)N_NODES * 256 * 2);
    __hip_bfloat16* Wt1  = (__hip_bfloat16*)alloc((size_t)256 * 256 * 2);
    __hip_bfloat16* Wt2  = (__hip_bfloat16*)alloc((size_t)256 * 256 * 2);
    __hip_bfloat16* Wt3  = (__hip_bfloat16*)alloc((size_t)256 * 256 * 2);
    float* asrc   = (float*)alloc((size_t)N_NODES * 4 * 4);
    float* adst   = (float*)alloc((size_t)N_NODES * 4 * 4);
    int*   deg    = (int*)alloc((size_t)N_NODES * 4);      // adjacent to cursor:
    int*   cursor = (int*)alloc((size_t)N_NODES * 4);      // single memset covers both
    int*   rowptr = (int*)alloc((size_t)(N_NODES + 1) * 4);
    int*   bsum   = (int*)alloc((size_t)SCAN_NB * 4);
    int*   csrsrc = (int*)alloc((size_t)E_TOT * 4);
    float* pmean  = (float*)alloc((size_t)N_GRAPH * 256 * 4);
    float* hidden = (float*)alloc((size_t)N_GRAPH * NHID * 4);
    (void)ws_size; (void)n_in; (void)in_sizes; (void)out_size;

    hipMemsetAsync(deg, 0, (size_t)N_NODES * 4 * 2, stream);   // deg + cursor

    conv_wt3_kernel<<<dim3(256, 3), 256, 0, stream>>>(W1, W2, W3, Wt1, Wt2, Wt3);

    // CSR (multi-block scan)
    const int eb = (E_TOT + 255) / 256;
    count_deg_kernel<<<eb, 256, 0, stream>>>(ei, deg);
    scan_p1_kernel<<<SCAN_NB, 256, 0, stream>>>(deg, bsum);
    scan_p2_kernel<<<1, 256, 0, stream>>>(bsum);
    scan_p3_kernel<<<SCAN_NB, 256, 0, stream>>>(deg, bsum, rowptr);
    fill_csr_kernel<<<eb, 256, 0, stream>>>(ei, rowptr, cursor, csrsrc);

    const dim3 ggrid(125, 2);   // 125*320 = 40000 rows exact; y = column half

    // layer 1 (A = x, fp32, cast fused into A-tile loads)
    gemm_mfma_kernel<1><<<ggrid, 512, 0, stream>>>(x, Wt1, hA, as1, ad1, asrc, adst);
    gat_fused_agg<<<N_NODES, 256, 0, stream>>>(hA, asrc, adst, rowptr, csrsrc, b1, hB, 1);
    // layer 2
    gemm_mfma_kernel<0><<<ggrid, 512, 0, stream>>>(hB, Wt2, hA, as2, ad2, asrc, adst);
    gat_fused_agg<<<N_NODES, 256, 0, stream>>>(hA, asrc, adst, rowptr, csrsrc, b2, hB, 1);
    // layer 3
    gemm_mfma_kernel<0><<<ggrid, 512, 0, stream>>>(hB, Wt3, hA, as3, ad3, asrc, adst);
    gat_fused_agg<<<N_NODES, 256, 0, stream>>>(hA, asrc, adst, rowptr, csrsrc, b3, hB, 0);

    // pool (mean) + weight-stationary MLP
    pool_kernel<<<N_GRAPH, 256, 0, stream>>>(hB, batch, pmean);
    mlp1_tiled<<<NHID / 64, 256, 0, stream>>>(pmean, Wm1, bm1, hidden);
    mlp2_tiled<<<NOUT / 64, 256, 0, stream>>>(hidden, Wm2, bm2, out);
}

// Round 12
// 435.331 us; speedup vs baseline: 1.2816x; 1.2816x over previous
//
#include <hip/hip_runtime.h>
#include <hip/hip_bf16.h>
#include <math.h>

#define N_NODES 40000
#define N_EDGES 640000
#define N_GRAPH 64
#define HEADS 4
#define CHAN 64
#define HC 256          // HEADS*CHAN
#define NHID 1024
#define NOUT 768
#define E_TOT (N_EDGES + N_NODES)
#define SCAN_NB ((N_NODES + 255) / 256)   // 157

typedef __attribute__((ext_vector_type(8))) short bf16x8;
typedef __attribute__((ext_vector_type(4))) float f32x4;

__device__ inline float bflo(unsigned u) { return __uint_as_float(u << 16); }
__device__ inline float bfhi(unsigned u) { return __uint_as_float(u & 0xffff0000u); }

__device__ inline unsigned bfbits(float f) {
    __hip_bfloat16 b = __float2bfloat16(f);
    return (unsigned)*reinterpret_cast<unsigned short*>(&b);
}
__device__ inline unsigned pk2bf(float lo, float hi) {
    return bfbits(lo) | (bfbits(hi) << 16);
}

// ---------------- weight transpose (all 3 layers, one launch) ----------------

__global__ void conv_wt3_kernel(const float* __restrict__ W1, const float* __restrict__ W2,
                                const float* __restrict__ W3, __hip_bfloat16* __restrict__ T1,
                                __hip_bfloat16* __restrict__ T2, __hip_bfloat16* __restrict__ T3) {
    const float* W = (blockIdx.y == 0) ? W1 : (blockIdx.y == 1) ? W2 : W3;
    __hip_bfloat16* T = (blockIdx.y == 0) ? T1 : (blockIdx.y == 1) ? T2 : T3;
    int k = blockIdx.x, n = threadIdx.x;
    T[(size_t)n * 256 + k] = __float2bfloat16(W[(size_t)k * 256 + n]);
}

// ---------------- CSR build ----------------

__global__ void count_deg_kernel(const int* __restrict__ ei, int* __restrict__ deg) {
    int i = blockIdx.x * blockDim.x + threadIdx.x;
    if (i >= E_TOT) return;
    int dst = (i < N_EDGES) ? ei[N_EDGES + i] : (i - N_EDGES);
    atomicAdd(&deg[dst], 1);
}

__global__ __launch_bounds__(256)
void scan_p1_kernel(const int* __restrict__ deg, int* __restrict__ bsum) {
    const int b = blockIdx.x, t = threadIdx.x;
    const int i = b * 256 + t;
    int v = (i < N_NODES) ? deg[i] : 0;
    #pragma unroll
    for (int off = 1; off < 64; off <<= 1) v += __shfl_xor(v, off, 64);
    __shared__ int ws[4];
    if ((t & 63) == 0) ws[t >> 6] = v;
    __syncthreads();
    if (t == 0) bsum[b] = ws[0] + ws[1] + ws[2] + ws[3];
}

__global__ __launch_bounds__(256)
void scan_p2_kernel(int* __restrict__ bsum) {     // single block; SCAN_NB <= 256
    __shared__ int s[256];
    const int t = threadIdx.x;
    int v = (t < SCAN_NB) ? bsum[t] : 0;
    s[t] = v;
    __syncthreads();
    #pragma unroll
    for (int off = 1; off < 256; off <<= 1) {
        int x = (t >= off) ? s[t - off] : 0;
        __syncthreads();
        s[t] += x;
        __syncthreads();
    }
    if (t < SCAN_NB) bsum[t] = s[t] - v;          // exclusive block offset
}

__global__ __launch_bounds__(256)
void scan_p3_kernel(const int* __restrict__ deg, const int* __restrict__ bsum,
                    int* __restrict__ rowptr) {
    __shared__ int s[256];
    const int b = blockIdx.x, t = threadIdx.x;
    const int i = b * 256 + t;
    int v = (i < N_NODES) ? deg[i] : 0;
    s[t] = v;
    __syncthreads();
    #pragma unroll
    for (int off = 1; off < 256; off <<= 1) {
        int x = (t >= off) ? s[t - off] : 0;
        __syncthreads();
        s[t] += x;
        __syncthreads();
    }
    if (i < N_NODES) rowptr[i] = bsum[b] + s[t] - v;
    if (i == 0) rowptr[N_NODES] = E_TOT;          // total is static
}

__global__ void fill_csr_kernel(const int* __restrict__ ei, const int* __restrict__ rowptr,
                                int* __restrict__ cursor, int* __restrict__ csr_src) {
    int i = blockIdx.x * blockDim.x + threadIdx.x;
    if (i >= E_TOT) return;
    int src, dst;
    if (i < N_EDGES) { src = ei[i]; dst = ei[N_EDGES + i]; }
    else             { src = dst = i - N_EDGES; }
    int pos = atomicAdd(&cursor[dst], 1);
    csr_src[rowptr[dst] + pos] = src;
}

// ---------------- bf16 MFMA GEMM: W-resident-in-LDS, B-frags in registers ----------------
// grid (125, 2): blockIdx.y = column half (2 heads). Block = 8 waves (512 thr).
// Stage 64KB W-half into LDS ONCE (XOR-swizzled), one barrier; each wave pulls its head's
// B fragments into 128 persistent VGPRs; then waves independently stream 16-row A tiles.

template<int CAST>
__global__ __launch_bounds__(512, 2)
void gemm_mfma_kernel(const void* __restrict__ Ain, const __hip_bfloat16* __restrict__ Wt,
                      __hip_bfloat16* __restrict__ C,
                      const float* __restrict__ a_s, const float* __restrict__ a_d,
                      float* __restrict__ asrc, float* __restrict__ adst) {
    __shared__ ushort Wl[128 * 256];    // 64 KB, 16B chunks XOR-swizzled: slot = q ^ (col&7)

    const int tid = threadIdx.x;
    const int lane = tid & 63;
    const int l15 = lane & 15, lq = lane >> 4;
    const int w = tid >> 6;
    const int hsel = w >> 2;
    const int stripe = w & 3;
    const int head = blockIdx.y * 2 + hsel;
    const int row_base = blockIdx.x * 320;

    // ---- stage W column-half (128 cols x 256 k) into LDS, swizzled
    {
        const int col = tid >> 2;                 // 0..127
        const char* Wb = (const char*)(Wt + (size_t)(blockIdx.y * 128 + col) * 256);
        #pragma unroll
        for (int j = 0; j < 8; j++) {
            int q = (tid & 3) * 8 + j;            // 16B chunk 0..31
            uint4 v = *reinterpret_cast<const uint4*>(Wb + q * 16);
            *reinterpret_cast<uint4*>(&Wl[col * 256 + ((q ^ (col & 7)) * 8)]) = v;
        }
    }
    __syncthreads();

    // ---- this wave's B fragments -> persistent registers (128 VGPRs)
    bf16x8 b[8][4];
    #pragma unroll
    for (int kt = 0; kt < 8; kt++)
        #pragma unroll
        for (int n = 0; n < 4; n++) {
            int cl = hsel * 64 + n * 16 + l15;
            int q = kt * 4 + lq;
            b[kt][n] = *reinterpret_cast<const bf16x8*>(&Wl[cl * 256 + ((q ^ (cl & 7)) * 8)]);
        }

    float was[4], wad[4];
    #pragma unroll
    for (int n = 0; n < 4; n++) {
        was[n] = a_s[head * 64 + n * 16 + l15];
        wad[n] = a_d[head * 64 + n * 16 + l15];
    }

    auto loadA = [&](int T, bf16x8* a) {
        const int row = row_base + T * 16 + l15;
        if (CAST) {
            const float* Af = (const float*)Ain;
            #pragma unroll
            for (int kt = 0; kt < 8; kt++) {
                float4 u0 = *reinterpret_cast<const float4*>(&Af[(size_t)row * 256 + kt * 32 + lq * 8]);
                float4 u1 = *reinterpret_cast<const float4*>(&Af[(size_t)row * 256 + kt * 32 + lq * 8 + 4]);
                uint4 uv = make_uint4(pk2bf(u0.x, u0.y), pk2bf(u0.z, u0.w),
                                      pk2bf(u1.x, u1.y), pk2bf(u1.z, u1.w));
                a[kt] = *reinterpret_cast<bf16x8*>(&uv);
            }
        } else {
            const __hip_bfloat16* Ab = (const __hip_bfloat16*)Ain;
            #pragma unroll
            for (int kt = 0; kt < 8; kt++) {
                uint4 uv = *reinterpret_cast<const uint4*>(&Ab[(size_t)row * 256 + kt * 32 + lq * 8]);
                a[kt] = *reinterpret_cast<bf16x8*>(&uv);
            }
        }
    };

    bf16x8 aA[8], aB[8];
    loadA(stripe, aA);
    #pragma unroll
    for (int ti = 0; ti < 5; ti++) {
        const int T = stripe + ti * 4;
        if (ti < 4) loadA(T + 4, aB);             // prefetch next tile under the MFMAs
        f32x4 acc[4];
        #pragma unroll
        for (int n = 0; n < 4; n++) acc[n] = (f32x4){0.f, 0.f, 0.f, 0.f};
        #pragma unroll
        for (int kt = 0; kt < 8; kt++)
            #pragma unroll
            for (int n = 0; n < 4; n++)
                acc[n] = __builtin_amdgcn_mfma_f32_16x16x32_bf16(aA[kt], b[kt][n], acc[n], 0, 0, 0);

        #pragma unroll
        for (int reg = 0; reg < 4; reg++) {
            float ps = 0.f, pd = 0.f;
            #pragma unroll
            for (int n = 0; n < 4; n++) {
                float v = acc[n][reg];
                ps = fmaf(v, was[n], ps);
                pd = fmaf(v, wad[n], pd);
            }
            #pragma unroll
            for (int off = 1; off < 16; off <<= 1) {
                ps += __shfl_xor(ps, off, 16);
                pd += __shfl_xor(pd, off, 16);
            }
            const int row = row_base + T * 16 + lq * 4 + reg;
            if (l15 == 0) {
                asrc[row * 4 + head] = ps;
                adst[row * 4 + head] = pd;
            }
        }
        #pragma unroll
        for (int n = 0; n < 4; n++)
            #pragma unroll
            for (int reg = 0; reg < 4; reg++) {
                float v = acc[n][reg];
                float vp = __shfl_xor(v, 1, 16);   // partner column
                const int row = row_base + T * 16 + lq * 4 + reg;
                if (!(l15 & 1)) {
                    unsigned pk = pk2bf(v, vp);
                    *reinterpret_cast<unsigned*>(&C[(size_t)row * 256 + head * 64 + n * 16 + l15]) = pk;
                }
            }
        #pragma unroll
        for (int kk = 0; kk < 8; kk++) aA[kk] = aB[kk];
    }
}

// ---------------- fused edge-softmax + aggregation (max-free, wave-per-head) ----------------

#define ACHUNK 256

__global__ __launch_bounds__(256)
void gat_fused_agg(const __hip_bfloat16* __restrict__ h, const float* __restrict__ asrc,
                   const float* __restrict__ adst, const int* __restrict__ rowptr,
                   const int* __restrict__ csr_src, const float* __restrict__ bias,
                   __hip_bfloat16* __restrict__ out, int do_relu) {
    __shared__ int   s_src[ACHUNK];
    __shared__ float s_w[ACHUNK][5];    // pad 4->5: conflict-free phase-0 writes
    __shared__ float s_acc[8][HC];
    __shared__ float s_sum[4];

    const int n = blockIdx.x;
    const int t = threadIdx.x;
    const int lane = t & 63;
    const int wid = t >> 6;         // wave id == head in phase 0
    const int grp = t >> 5;         // phase-1 group (edge parity)
    const int gl  = t & 31;         // lane in group; channels gl*8..gl*8+7
    const int h3  = gl >> 3;        // head owning those channels
    const int start = rowptr[n];
    const int deg = rowptr[n + 1] - start;
    const float ad = adst[n * 4 + wid];

    float ssum = 0.f;
    float acc[8] = {0.f, 0.f, 0.f, 0.f, 0.f, 0.f, 0.f, 0.f};

    for (int c0 = 0; c0 < deg; c0 += ACHUNK) {
        const int cn = min(ACHUNK, deg - c0);
        if (c0) __syncthreads();
        for (int e = lane; e < cn; e += 64) {
            int src = csr_src[start + c0 + e];
            if (wid == 0) s_src[e] = src;
            float sc = asrc[src * 4 + wid] + ad;
            sc = (sc >= 0.f) ? sc : 0.2f * sc;   // leaky relu 0.2
            float w = __expf(sc);
            s_w[e][wid] = w;
            ssum += w;
        }
        __syncthreads();
        #pragma unroll 2
        for (int e = grp; e < cn; e += 8) {
            float w = s_w[e][h3];
            uint4 v = *reinterpret_cast<const uint4*>(&h[(size_t)s_src[e] * HC + gl * 8]);
            acc[0] = fmaf(w, bflo(v.x), acc[0]);
            acc[1] = fmaf(w, bfhi(v.x), acc[1]);
            acc[2] = fmaf(w, bflo(v.y), acc[2]);
            acc[3] = fmaf(w, bfhi(v.y), acc[3]);
            acc[4] = fmaf(w, bflo(v.z), acc[4]);
            acc[5] = fmaf(w, bfhi(v.z), acc[5]);
            acc[6] = fmaf(w, bflo(v.w), acc[6]);
            acc[7] = fmaf(w, bfhi(v.w), acc[7]);
        }
    }
    #pragma unroll
    for (int off = 1; off < 64; off <<= 1) ssum += __shfl_xor(ssum, off, 64);
    if (lane == 0) s_sum[wid] = ssum;
    *reinterpret_cast<float4*>(&s_acc[grp][gl * 8])     = make_float4(acc[0], acc[1], acc[2], acc[3]);
    *reinterpret_cast<float4*>(&s_acc[grp][gl * 8 + 4]) = make_float4(acc[4], acc[5], acc[6], acc[7]);
    __syncthreads();
    float tot = 0.f;
    #pragma unroll
    for (int g = 0; g < 8; g++) tot += s_acc[g][t];
    float r = tot / s_sum[t >> 6] + bias[t];
    if (do_relu) r = fmaxf(r, 0.f);
    out[(size_t)n * HC + t] = __float2bfloat16(r);
}

// ---------------- fused pool + MLP layer 1 (one block per graph) ----------------

__global__ __launch_bounds__(1024)
void pool_mlp1_kernel(const __hip_bfloat16* __restrict__ h, const int* __restrict__ batch,
                      const float* __restrict__ Wm1, const float* __restrict__ bm1,
                      float* __restrict__ hidden) {
    __shared__ float s_part[4][256];
    __shared__ float row[256];
    const int g = blockIdx.x, t = threadIdx.x;
    int lo = 0, hi = N_NODES;
    while (lo < hi) { int mid = (lo + hi) >> 1; if (batch[mid] < g) lo = mid + 1; else hi = mid; }
    const int start = lo;
    lo = 0; hi = N_NODES;
    while (lo < hi) { int mid = (lo + hi) >> 1; if (batch[mid] < g + 1) lo = mid + 1; else hi = mid; }
    const int end = lo;

    const int sub = t >> 8, ch = t & 255;
    float a = 0.f;
    for (int n = start + sub; n < end; n += 4)
        a += __bfloat162float(h[(size_t)n * HC + ch]);
    s_part[sub][ch] = a;
    __syncthreads();
    if (t < 256) {
        float c = (float)max(end - start, 1);
        row[t] = (s_part[0][t] + s_part[1][t] + s_part[2][t] + s_part[3][t]) / c;
    }
    __syncthreads();
    float acc = bm1[t];
    for (int k = 0; k < 256; k++) acc = fmaf(row[k], Wm1[(size_t)k * NHID + t], acc);
    hidden[(size_t)g * NHID + t] = fmaxf(acc, 0.f);
}

__global__ __launch_bounds__(768)
void mlp2_kernel(const float* __restrict__ hidden, const float* __restrict__ W,
                 const float* __restrict__ b, float* __restrict__ out) {
    __shared__ float row[NHID];
    const int g = blockIdx.x, t = threadIdx.x;
    row[t] = hidden[g * NHID + t];
    if (t < NHID - NOUT) row[NOUT + t] = hidden[g * NHID + NOUT + t];
    __syncthreads();
    float acc = b[t];
    for (int k = 0; k < NHID; k++) acc = fmaf(row[k], W[(size_t)k * NOUT + t], acc);
    out[g * NOUT + t] = acc;
}

// ---------------- launch ----------------

extern "C" void kernel_launch(void* const* d_in, const int* in_sizes, int n_in,
                              void* d_out, int out_size, void* d_ws, size_t ws_size,
                              hipStream_t stream) {
    const float* x  = (const float*)d_in[0];
    const int* ei   = (const int*)d_in[1];
    const int* batch = (const int*)d_in[2];
    const float* W1 = (const float*)d_in[3];
    const float* as1 = (const float*)d_in[4];
    const float* ad1 = (const float*)d_in[5];
    const float* b1 = (const float*)d_in[6];
    const float* W2 = (const float*)d_in[7];
    const float* as2 = (const float*)d_in[8];
    const float* ad2 = (const float*)d_in[9];
    const float* b2 = (const float*)d_in[10];
    const float* W3 = (const float*)d_in[11];
    const float* as3 = (const float*)d_in[12];
    const float* ad3 = (const float*)d_in[13];
    const float* b3 = (const float*)d_in[14];
    const float* Wm1 = (const float*)d_in[15];
    const float* bm1 = (const float*)d_in[16];
    const float* Wm2 = (const float*)d_in[17];
    const float* bm2 = (const float*)d_in[18];
    float* out = (float*)d_out;

    char* base = (char*)d_ws;
    size_t off = 0;
    auto alloc = [&](size_t bytes) { char* p = base + off; off = (off + bytes + 255) & ~(size_t)255; return p; };
    __hip_bfloat16* hA   = (__hip_bfloat16*)alloc((size_t)N_NODES * 256 * 2);
    __hip_bfloat16* hB   = (__hip_bfloat16*)alloc((size_t)N_NODES * 256 * 2);
    __hip_bfloat16* Wt1  = (__hip_bfloat16*)alloc((size_t)256 * 256 * 2);
    __hip_bfloat16* Wt2  = (__hip_bfloat16*)alloc((size_t)256 * 256 * 2);
    __hip_bfloat16* Wt3  = (__hip_bfloat16*)alloc((size_t)256 * 256 * 2);
    float* asrc   = (float*)alloc((size_t)N_NODES * 4 * 4);
    float* adst   = (float*)alloc((size_t)N_NODES * 4 * 4);
    int*   deg    = (int*)alloc((size_t)N_NODES * 4);      // adjacent to cursor:
    int*   cursor = (int*)alloc((size_t)N_NODES * 4);      // single memset covers both
    int*   rowptr = (int*)alloc((size_t)(N_NODES + 1) * 4);
    int*   bsum   = (int*)alloc((size_t)SCAN_NB * 4);
    int*   csrsrc = (int*)alloc((size_t)E_TOT * 4);
    float* hidden = (float*)alloc((size_t)N_GRAPH * NHID * 4);
    (void)ws_size; (void)n_in; (void)in_sizes; (void)out_size;

    hipMemsetAsync(deg, 0, (size_t)N_NODES * 4 * 2, stream);   // deg + cursor

    conv_wt3_kernel<<<dim3(256, 3), 256, 0, stream>>>(W1, W2, W3, Wt1, Wt2, Wt3);

    // CSR (multi-block scan)
    const int eb = (E_TOT + 255) / 256;
    count_deg_kernel<<<eb, 256, 0, stream>>>(ei, deg);
    scan_p1_kernel<<<SCAN_NB, 256, 0, stream>>>(deg, bsum);
    scan_p2_kernel<<<1, 256, 0, stream>>>(bsum);
    scan_p3_kernel<<<SCAN_NB, 256, 0, stream>>>(deg, bsum, rowptr);
    fill_csr_kernel<<<eb, 256, 0, stream>>>(ei, rowptr, cursor, csrsrc);

    const dim3 ggrid(125, 2);   // 125*320 = 40000 rows exact; y = column half

    // layer 1 (A = x, fp32, cast fused into A-tile loads)
    gemm_mfma_kernel<1><<<ggrid, 512, 0, stream>>>(x, Wt1, hA, as1, ad1, asrc, adst);
    gat_fused_agg<<<N_NODES, 256, 0, stream>>>(hA, asrc, adst, rowptr, csrsrc, b1, hB, 1);
    // layer 2
    gemm_mfma_kernel<0><<<ggrid, 512, 0, stream>>>(hB, Wt2, hA, as2, ad2, asrc, adst);
    gat_fused_agg<<<N_NODES, 256, 0, stream>>>(hA, asrc, adst, rowptr, csrsrc, b2, hB, 1);
    // layer 3
    gemm_mfma_kernel<0><<<ggrid, 512, 0, stream>>>(hB, Wt3, hA, as3, ad3, asrc, adst);
    gat_fused_agg<<<N_NODES, 256, 0, stream>>>(hA, asrc, adst, rowptr, csrsrc, b3, hB, 0);

    // fused pool+mlp1, then mlp2
    pool_mlp1_kernel<<<N_GRAPH, 1024, 0, stream>>>(hB, batch, Wm1, bm1, hidden);
    mlp2_kernel<<<N_GRAPH, NOUT, 0, stream>>>(hidden, Wm2, bm2, out);
}

// Round 13
// 410.262 us; speedup vs baseline: 1.3599x; 1.0611x over previous
//
#include <hip/hip_runtime.h>
#include <hip/hip_bf16.h>
#include <math.h>

#define N_NODES 40000
#define N_EDGES 640000
#define N_GRAPH 64
#define HEADS 4
#define CHAN 64
#define HC 256          // HEADS*CHAN
#define NHID 1024
#define NOUT 768
#define E_TOT (N_EDGES + N_NODES)
#define SCAN_NB ((N_NODES + 255) / 256)   // 157

typedef __attribute__((ext_vector_type(8))) short bf16x8;
typedef __attribute__((ext_vector_type(4))) float f32x4;

__device__ inline float bflo(unsigned u) { return __uint_as_float(u << 16); }
__device__ inline float bfhi(unsigned u) { return __uint_as_float(u & 0xffff0000u); }

__device__ inline unsigned bfbits(float f) {
    __hip_bfloat16 b = __float2bfloat16(f);
    return (unsigned)*reinterpret_cast<unsigned short*>(&b);
}
__device__ inline unsigned pk2bf(float lo, float hi) {
    return bfbits(lo) | (bfbits(hi) << 16);
}

// ---------------- weight transpose (all 3 layers, one launch) ----------------

__global__ void conv_wt3_kernel(const float* __restrict__ W1, const float* __restrict__ W2,
                                const float* __restrict__ W3, __hip_bfloat16* __restrict__ T1,
                                __hip_bfloat16* __restrict__ T2, __hip_bfloat16* __restrict__ T3) {
    const float* W = (blockIdx.y == 0) ? W1 : (blockIdx.y == 1) ? W2 : W3;
    __hip_bfloat16* T = (blockIdx.y == 0) ? T1 : (blockIdx.y == 1) ? T2 : T3;
    int k = blockIdx.x, n = threadIdx.x;
    T[(size_t)n * 256 + k] = __float2bfloat16(W[(size_t)k * 256 + n]);
}

// ---------------- CSR build ----------------

__global__ void count_deg_kernel(const int* __restrict__ ei, int* __restrict__ deg) {
    int i = blockIdx.x * blockDim.x + threadIdx.x;
    if (i >= E_TOT) return;
    int dst = (i < N_EDGES) ? ei[N_EDGES + i] : (i - N_EDGES);
    atomicAdd(&deg[dst], 1);
}

__global__ __launch_bounds__(256)
void scan_p1_kernel(const int* __restrict__ deg, int* __restrict__ bsum) {
    const int b = blockIdx.x, t = threadIdx.x;
    const int i = b * 256 + t;
    int v = (i < N_NODES) ? deg[i] : 0;
    #pragma unroll
    for (int off = 1; off < 64; off <<= 1) v += __shfl_xor(v, off, 64);
    __shared__ int ws[4];
    if ((t & 63) == 0) ws[t >> 6] = v;
    __syncthreads();
    if (t == 0) bsum[b] = ws[0] + ws[1] + ws[2] + ws[3];
}

__global__ __launch_bounds__(256)
void scan_p2_kernel(int* __restrict__ bsum) {     // single block; SCAN_NB <= 256
    __shared__ int s[256];
    const int t = threadIdx.x;
    int v = (t < SCAN_NB) ? bsum[t] : 0;
    s[t] = v;
    __syncthreads();
    #pragma unroll
    for (int off = 1; off < 256; off <<= 1) {
        int x = (t >= off) ? s[t - off] : 0;
        __syncthreads();
        s[t] += x;
        __syncthreads();
    }
    if (t < SCAN_NB) bsum[t] = s[t] - v;          // exclusive block offset
}

__global__ __launch_bounds__(256)
void scan_p3_kernel(const int* __restrict__ deg, const int* __restrict__ bsum,
                    int* __restrict__ rowptr) {
    __shared__ int s[256];
    const int b = blockIdx.x, t = threadIdx.x;
    const int i = b * 256 + t;
    int v = (i < N_NODES) ? deg[i] : 0;
    s[t] = v;
    __syncthreads();
    #pragma unroll
    for (int off = 1; off < 256; off <<= 1) {
        int x = (t >= off) ? s[t - off] : 0;
        __syncthreads();
        s[t] += x;
        __syncthreads();
    }
    if (i < N_NODES) rowptr[i] = bsum[b] + s[t] - v;
    if (i == 0) rowptr[N_NODES] = E_TOT;          // total is static
}

__global__ void fill_csr_kernel(const int* __restrict__ ei, const int* __restrict__ rowptr,
                                int* __restrict__ cursor, int* __restrict__ csr_src) {
    int i = blockIdx.x * blockDim.x + threadIdx.x;
    if (i >= E_TOT) return;
    int src, dst;
    if (i < N_EDGES) { src = ei[i]; dst = ei[N_EDGES + i]; }
    else             { src = dst = i - N_EDGES; }
    int pos = atomicAdd(&cursor[dst], 1);
    csr_src[rowptr[dst] + pos] = src;
}

// ---------------- bf16 MFMA GEMM: W-resident-in-LDS, B-frags in registers ----------------
// grid (125, 2): blockIdx.y = column half (2 heads). Block = 8 waves (512 thr).
// Stage 64KB W-half into LDS ONCE (XOR-swizzled); each wave pulls its head's B fragments
// into 128 persistent VGPRs; Wl is then DEAD and reused as per-wave epilogue strips.
// Main loop: zero barriers, reg-prefetched A tiles. Epilogue: LDS repack -> uint4 stores.

template<int CAST>
__global__ __launch_bounds__(512, 2)
void gemm_mfma_kernel(const void* __restrict__ Ain, const __hip_bfloat16* __restrict__ Wt,
                      __hip_bfloat16* __restrict__ C,
                      const float* __restrict__ a_s, const float* __restrict__ a_d,
                      float* __restrict__ asrc, float* __restrict__ adst) {
    __shared__ ushort Wl[128 * 256];    // 64 KB; 16B chunks XOR-swizzled: slot = q ^ (col&7)

    const int tid = threadIdx.x;
    const int lane = tid & 63;
    const int l15 = lane & 15, lq = lane >> 4;
    const int w = tid >> 6;
    const int hsel = w >> 2;
    const int stripe = w & 3;
    const int head = blockIdx.y * 2 + hsel;
    const int row_base = blockIdx.x * 320;

    // ---- stage W column-half (128 cols x 256 k) into LDS, swizzled
    {
        const int col = tid >> 2;                 // 0..127
        const char* Wb = (const char*)(Wt + (size_t)(blockIdx.y * 128 + col) * 256);
        #pragma unroll
        for (int j = 0; j < 8; j++) {
            int q = (tid & 3) * 8 + j;            // 16B chunk 0..31
            uint4 v = *reinterpret_cast<const uint4*>(Wb + q * 16);
            *reinterpret_cast<uint4*>(&Wl[col * 256 + ((q ^ (col & 7)) * 8)]) = v;
        }
    }
    __syncthreads();

    // ---- this wave's B fragments -> persistent registers (128 VGPRs)
    bf16x8 b[8][4];
    #pragma unroll
    for (int kt = 0; kt < 8; kt++)
        #pragma unroll
        for (int n = 0; n < 4; n++) {
            int cl = hsel * 64 + n * 16 + l15;
            int q = kt * 4 + lq;
            b[kt][n] = *reinterpret_cast<const bf16x8*>(&Wl[cl * 256 + ((q ^ (cl & 7)) * 8)]);
        }
    __syncthreads();    // all frag reads done -> Wl reusable as epilogue strips

    float* strip = reinterpret_cast<float*>(Wl) + w * (16 * 68);   // 4.25KB/wave, wave-private

    float was[4], wad[4];
    #pragma unroll
    for (int n = 0; n < 4; n++) {
        was[n] = a_s[head * 64 + n * 16 + l15];
        wad[n] = a_d[head * 64 + n * 16 + l15];
    }

    auto loadA = [&](int T, bf16x8* a) {
        const int row = row_base + T * 16 + l15;
        if (CAST) {
            const float* Af = (const float*)Ain;
            #pragma unroll
            for (int kt = 0; kt < 8; kt++) {
                float4 u0 = *reinterpret_cast<const float4*>(&Af[(size_t)row * 256 + kt * 32 + lq * 8]);
                float4 u1 = *reinterpret_cast<const float4*>(&Af[(size_t)row * 256 + kt * 32 + lq * 8 + 4]);
                uint4 uv = make_uint4(pk2bf(u0.x, u0.y), pk2bf(u0.z, u0.w),
                                      pk2bf(u1.x, u1.y), pk2bf(u1.z, u1.w));
                a[kt] = *reinterpret_cast<bf16x8*>(&uv);
            }
        } else {
            const __hip_bfloat16* Ab = (const __hip_bfloat16*)Ain;
            #pragma unroll
            for (int kt = 0; kt < 8; kt++) {
                uint4 uv = *reinterpret_cast<const uint4*>(&Ab[(size_t)row * 256 + kt * 32 + lq * 8]);
                a[kt] = *reinterpret_cast<bf16x8*>(&uv);
            }
        }
    };

    bf16x8 aA[8], aB[8];
    loadA(stripe, aA);
    #pragma unroll
    for (int ti = 0; ti < 5; ti++) {
        const int T = stripe + ti * 4;
        if (ti < 4) loadA(T + 4, aB);             // prefetch next tile under the MFMAs
        f32x4 acc[4];
        #pragma unroll
        for (int n = 0; n < 4; n++) acc[n] = (f32x4){0.f, 0.f, 0.f, 0.f};
        #pragma unroll
        for (int kt = 0; kt < 8; kt++)
            #pragma unroll
            for (int n = 0; n < 4; n++)
                acc[n] = __builtin_amdgcn_mfma_f32_16x16x32_bf16(aA[kt], b[kt][n], acc[n], 0, 0, 0);

        // fused alpha dot in fragment layout (cols n*16+l15, reduce over l15)
        #pragma unroll
        for (int reg = 0; reg < 4; reg++) {
            float ps = 0.f, pd = 0.f;
            #pragma unroll
            for (int n = 0; n < 4; n++) {
                float v = acc[n][reg];
                ps = fmaf(v, was[n], ps);
                pd = fmaf(v, wad[n], pd);
            }
            #pragma unroll
            for (int off = 1; off < 16; off <<= 1) {
                ps += __shfl_xor(ps, off, 16);
                pd += __shfl_xor(pd, off, 16);
            }
            const int row = row_base + T * 16 + lq * 4 + reg;
            if (l15 == 0) {
                asrc[row * 4 + head] = ps;
                adst[row * 4 + head] = pd;
            }
        }
        // repack acc through wave-private LDS strip -> coalesced uint4 C stores
        #pragma unroll
        for (int n = 0; n < 4; n++)
            #pragma unroll
            for (int reg = 0; reg < 4; reg++)
                strip[(lq * 4 + reg) * 68 + n * 16 + l15] = acc[n][reg];
        {
            const int r  = lane >> 2;             // output row within 16-row tile
            const int cq = lane & 3;              // 16-col quarter
            f32x4 c0 = *reinterpret_cast<const f32x4*>(&strip[r * 68 + cq * 16]);
            f32x4 c1 = *reinterpret_cast<const f32x4*>(&strip[r * 68 + cq * 16 + 4]);
            f32x4 c2 = *reinterpret_cast<const f32x4*>(&strip[r * 68 + cq * 16 + 8]);
            f32x4 c3 = *reinterpret_cast<const f32x4*>(&strip[r * 68 + cq * 16 + 12]);
            uint4 o0 = make_uint4(pk2bf(c0[0], c0[1]), pk2bf(c0[2], c0[3]),
                                  pk2bf(c1[0], c1[1]), pk2bf(c1[2], c1[3]));
            uint4 o1 = make_uint4(pk2bf(c2[0], c2[1]), pk2bf(c2[2], c2[3]),
                                  pk2bf(c3[0], c3[1]), pk2bf(c3[2], c3[3]));
            const int row = row_base + T * 16 + r;
            __hip_bfloat16* Cp = C + (size_t)row * 256 + head * 64 + cq * 16;
            *reinterpret_cast<uint4*>(Cp) = o0;
            *reinterpret_cast<uint4*>(Cp + 8) = o1;
        }
        #pragma unroll
        for (int kk = 0; kk < 8; kk++) aA[kk] = aB[kk];
    }
}

// ---------------- fused edge-softmax + aggregation (max-free, wave-per-head) ----------------

#define ACHUNK 256

__global__ __launch_bounds__(256)
void gat_fused_agg(const __hip_bfloat16* __restrict__ h, const float* __restrict__ asrc,
                   const float* __restrict__ adst, const int* __restrict__ rowptr,
                   const int* __restrict__ csr_src, const float* __restrict__ bias,
                   __hip_bfloat16* __restrict__ out, int do_relu) {
    __shared__ int   s_src[ACHUNK];
    __shared__ float s_w[ACHUNK][5];    // pad 4->5: conflict-free phase-0 writes
    __shared__ float s_acc[8][HC];
    __shared__ float s_sum[4];

    const int n = blockIdx.x;
    const int t = threadIdx.x;
    const int lane = t & 63;
    const int wid = t >> 6;         // wave id == head in phase 0
    const int grp = t >> 5;         // phase-1 group (edge parity)
    const int gl  = t & 31;         // lane in group; channels gl*8..gl*8+7
    const int h3  = gl >> 3;        // head owning those channels
    const int start = rowptr[n];
    const int deg = rowptr[n + 1] - start;
    const float ad = adst[n * 4 + wid];

    float ssum = 0.f;
    float acc[8] = {0.f, 0.f, 0.f, 0.f, 0.f, 0.f, 0.f, 0.f};

    for (int c0 = 0; c0 < deg; c0 += ACHUNK) {
        const int cn = min(ACHUNK, deg - c0);
        if (c0) __syncthreads();
        for (int e = lane; e < cn; e += 64) {
            int src = csr_src[start + c0 + e];
            if (wid == 0) s_src[e] = src;
            float sc = asrc[src * 4 + wid] + ad;
            sc = (sc >= 0.f) ? sc : 0.2f * sc;   // leaky relu 0.2
            float w = __expf(sc);
            s_w[e][wid] = w;
            ssum += w;
        }
        __syncthreads();
        #pragma unroll 2
        for (int e = grp; e < cn; e += 8) {
            float w = s_w[e][h3];
            uint4 v = *reinterpret_cast<const uint4*>(&h[(size_t)s_src[e] * HC + gl * 8]);
            acc[0] = fmaf(w, bflo(v.x), acc[0]);
            acc[1] = fmaf(w, bfhi(v.x), acc[1]);
            acc[2] = fmaf(w, bflo(v.y), acc[2]);
            acc[3] = fmaf(w, bfhi(v.y), acc[3]);
            acc[4] = fmaf(w, bflo(v.z), acc[4]);
            acc[5] = fmaf(w, bfhi(v.z), acc[5]);
            acc[6] = fmaf(w, bflo(v.w), acc[6]);
            acc[7] = fmaf(w, bfhi(v.w), acc[7]);
        }
    }
    #pragma unroll
    for (int off = 1; off < 64; off <<= 1) ssum += __shfl_xor(ssum, off, 64);
    if (lane == 0) s_sum[wid] = ssum;
    *reinterpret_cast<float4*>(&s_acc[grp][gl * 8])     = make_float4(acc[0], acc[1], acc[2], acc[3]);
    *reinterpret_cast<float4*>(&s_acc[grp][gl * 8 + 4]) = make_float4(acc[4], acc[5], acc[6], acc[7]);
    __syncthreads();
    float tot = 0.f;
    #pragma unroll
    for (int g = 0; g < 8; g++) tot += s_acc[g][t];
    float r = tot / s_sum[t >> 6] + bias[t];
    if (do_relu) r = fmaxf(r, 0.f);
    out[(size_t)n * HC + t] = __float2bfloat16(r);
}

// ---------------- fused pool + MLP layer 1 (one block per graph) ----------------

__global__ __launch_bounds__(1024)
void pool_mlp1_kernel(const __hip_bfloat16* __restrict__ h, const int* __restrict__ batch,
                      const float* __restrict__ Wm1, const float* __restrict__ bm1,
                      float* __restrict__ hidden) {
    __shared__ float s_part[4][256];
    __shared__ float row[256];
    const int g = blockIdx.x, t = threadIdx.x;
    int lo = 0, hi = N_NODES;
    while (lo < hi) { int mid = (lo + hi) >> 1; if (batch[mid] < g) lo = mid + 1; else hi = mid; }
    const int start = lo;
    lo = 0; hi = N_NODES;
    while (lo < hi) { int mid = (lo + hi) >> 1; if (batch[mid] < g + 1) lo = mid + 1; else hi = mid; }
    const int end = lo;

    const int sub = t >> 8, ch = t & 255;
    float a = 0.f;
    for (int n = start + sub; n < end; n += 4)
        a += __bfloat162float(h[(size_t)n * HC + ch]);
    s_part[sub][ch] = a;
    __syncthreads();
    if (t < 256) {
        float c = (float)max(end - start, 1);
        row[t] = (s_part[0][t] + s_part[1][t] + s_part[2][t] + s_part[3][t]) / c;
    }
    __syncthreads();
    float acc = bm1[t];
    for (int k = 0; k < 256; k++) acc = fmaf(row[k], Wm1[(size_t)k * NHID + t], acc);
    hidden[(size_t)g * NHID + t] = fmaxf(acc, 0.f);
}

// ---------------- split-K MLP layer 2 ----------------
// partial[ks][g][c] = sum_{k in slice ks} hidden[g][k] * Wm2[k][c]; 512 blocks.

__global__ __launch_bounds__(768)
void mlp2_partial(const float* __restrict__ hidden, const float* __restrict__ W,
                  float* __restrict__ partial) {
    __shared__ float row[128];
    const int g = blockIdx.x, ks = blockIdx.y, t = threadIdx.x;
    if (t < 128) row[t] = hidden[(size_t)g * NHID + ks * 128 + t];
    __syncthreads();
    float acc = 0.f;
    const float* Wp = W + (size_t)(ks * 128) * NOUT + t;
    #pragma unroll 4
    for (int k = 0; k < 128; k++) acc = fmaf(row[k], Wp[(size_t)k * NOUT], acc);
    partial[((size_t)ks * N_GRAPH + g) * NOUT + t] = acc;
}

__global__ __launch_bounds__(768)
void mlp2_reduce(const float* __restrict__ partial, const float* __restrict__ b,
                 float* __restrict__ out) {
    const int g = blockIdx.x, t = threadIdx.x;
    float acc = b[t];
    #pragma unroll
    for (int ks = 0; ks < 8; ks++)
        acc += partial[((size_t)ks * N_GRAPH + g) * NOUT + t];
    out[(size_t)g * NOUT + t] = acc;
}

// ---------------- launch ----------------

extern "C" void kernel_launch(void* const* d_in, const int* in_sizes, int n_in,
                              void* d_out, int out_size, void* d_ws, size_t ws_size,
                              hipStream_t stream) {
    const float* x  = (const float*)d_in[0];
    const int* ei   = (const int*)d_in[1];
    const int* batch = (const int*)d_in[2];
    const float* W1 = (const float*)d_in[3];
    const float* as1 = (const float*)d_in[4];
    const float* ad1 = (const float*)d_in[5];
    const float* b1 = (const float*)d_in[6];
    const float* W2 = (const float*)d_in[7];
    const float* as2 = (const float*)d_in[8];
    const float* ad2 = (const float*)d_in[9];
    const float* b2 = (const float*)d_in[10];
    const float* W3 = (const float*)d_in[11];
    const float* as3 = (const float*)d_in[12];
    const float* ad3 = (const float*)d_in[13];
    const float* b3 = (const float*)d_in[14];
    const float* Wm1 = (const float*)d_in[15];
    const float* bm1 = (const float*)d_in[16];
    const float* Wm2 = (const float*)d_in[17];
    const float* bm2 = (const float*)d_in[18];
    float* out = (float*)d_out;

    char* base = (char*)d_ws;
    size_t off = 0;
    auto alloc = [&](size_t bytes) { char* p = base + off; off = (off + bytes + 255) & ~(size_t)255; return p; };
    __hip_bfloat16* hA   = (__hip_bfloat16*)alloc((size_t)N_NODES * 256 * 2);
    __hip_bfloat16* hB   = (__hip_bfloat16*)alloc((size_t)N_NODES * 256 * 2);
    __hip_bfloat16* Wt1  = (__hip_bfloat16*)alloc((size_t)256 * 256 * 2);
    __hip_bfloat16* Wt2  = (__hip_bfloat16*)alloc((size_t)256 * 256 * 2);
    __hip_bfloat16* Wt3  = (__hip_bfloat16*)alloc((size_t)256 * 256 * 2);
    float* asrc   = (float*)alloc((size_t)N_NODES * 4 * 4);
    float* adst   = (float*)alloc((size_t)N_NODES * 4 * 4);
    int*   deg    = (int*)alloc((size_t)N_NODES * 4);      // adjacent to cursor:
    int*   cursor = (int*)alloc((size_t)N_NODES * 4);      // single memset covers both
    int*   rowptr = (int*)alloc((size_t)(N_NODES + 1) * 4);
    int*   bsum   = (int*)alloc((size_t)SCAN_NB * 4);
    int*   csrsrc = (int*)alloc((size_t)E_TOT * 4);
    float* hidden = (float*)alloc((size_t)N_GRAPH * NHID * 4);
    float* part2  = (float*)alloc((size_t)8 * N_GRAPH * NOUT * 4);
    (void)ws_size; (void)n_in; (void)in_sizes; (void)out_size;

    hipMemsetAsync(deg, 0, (size_t)N_NODES * 4 * 2, stream);   // deg + cursor

    conv_wt3_kernel<<<dim3(256, 3), 256, 0, stream>>>(W1, W2, W3, Wt1, Wt2, Wt3);

    // CSR (multi-block scan)
    const int eb = (E_TOT + 255) / 256;
    count_deg_kernel<<<eb, 256, 0, stream>>>(ei, deg);
    scan_p1_kernel<<<SCAN_NB, 256, 0, stream>>>(deg, bsum);
    scan_p2_kernel<<<1, 256, 0, stream>>>(bsum);
    scan_p3_kernel<<<SCAN_NB, 256, 0, stream>>>(deg, bsum, rowptr);
    fill_csr_kernel<<<eb, 256, 0, stream>>>(ei, rowptr, cursor, csrsrc);

    const dim3 ggrid(125, 2);   // 125*320 = 40000 rows exact; y = column half

    // layer 1 (A = x, fp32, cast fused into A-tile loads)
    gemm_mfma_kernel<1><<<ggrid, 512, 0, stream>>>(x, Wt1, hA, as1, ad1, asrc, adst);
    gat_fused_agg<<<N_NODES, 256, 0, stream>>>(hA, asrc, adst, rowptr, csrsrc, b1, hB, 1);
    // layer 2
    gemm_mfma_kernel<0><<<ggrid, 512, 0, stream>>>(hB, Wt2, hA, as2, ad2, asrc, adst);
    gat_fused_agg<<<N_NODES, 256, 0, stream>>>(hA, asrc, adst, rowptr, csrsrc, b2, hB, 1);
    // layer 3
    gemm_mfma_kernel<0><<<ggrid, 512, 0, stream>>>(hB, Wt3, hA, as3, ad3, asrc, adst);
    gat_fused_agg<<<N_NODES, 256, 0, stream>>>(hA, asrc, adst, rowptr, csrsrc, b3, hB, 0);

    // fused pool+mlp1, then split-K mlp2
    pool_mlp1_kernel<<<N_GRAPH, 1024, 0, stream>>>(hB, batch, Wm1, bm1, hidden);
    mlp2_partial<<<dim3(N_GRAPH, 8), 768, 0, stream>>>(hidden, Wm2, part2);
    mlp2_reduce<<<N_GRAPH, 768, 0, stream>>>(part2, bm2, out);
}

// Round 14
// 409.807 us; speedup vs baseline: 1.3614x; 1.0011x over previous
//
#include <hip/hip_runtime.h>
#include <hip/hip_bf16.h>
#include <math.h>

#define N_NODES 40000
#define N_EDGES 640000
#define N_GRAPH 64
#define HEADS 4
#define CHAN 64
#define HC 256          // HEADS*CHAN
#define NHID 1024
#define NOUT 768
#define E_TOT (N_EDGES + N_NODES)
#define SCAN_NB ((N_NODES + 255) / 256)   // 157

typedef __attribute__((ext_vector_type(8))) short bf16x8;
typedef __attribute__((ext_vector_type(4))) float f32x4;

__device__ inline float bflo(unsigned u) { return __uint_as_float(u << 16); }
__device__ inline float bfhi(unsigned u) { return __uint_as_float(u & 0xffff0000u); }

__device__ inline unsigned bfbits(float f) {
    __hip_bfloat16 b = __float2bfloat16(f);
    return (unsigned)*reinterpret_cast<unsigned short*>(&b);
}
__device__ inline unsigned pk2bf(float lo, float hi) {
    return bfbits(lo) | (bfbits(hi) << 16);
}

// ---------------- weight transpose: LDS-tiled, coalesced writes ----------------
// grid (4,4,3): 64x64 tile of W[k][n] -> T[n][k]. Reads and writes both coalesced.

__global__ __launch_bounds__(256)
void conv_wt3_kernel(const float* __restrict__ W1, const float* __restrict__ W2,
                     const float* __restrict__ W3, __hip_bfloat16* __restrict__ T1,
                     __hip_bfloat16* __restrict__ T2, __hip_bfloat16* __restrict__ T3) {
    const float* W = (blockIdx.z == 0) ? W1 : (blockIdx.z == 1) ? W2 : W3;
    __hip_bfloat16* T = (blockIdx.z == 0) ? T1 : (blockIdx.z == 1) ? T2 : T3;
    __shared__ float tile[64][65];
    const int tx = threadIdx.x & 63, ty = threadIdx.x >> 6;
    const int k0 = blockIdx.x * 64, n0 = blockIdx.y * 64;
    #pragma unroll
    for (int r = ty; r < 64; r += 4)
        tile[r][tx] = W[(size_t)(k0 + r) * 256 + n0 + tx];
    __syncthreads();
    #pragma unroll
    for (int r = ty; r < 64; r += 4)
        T[(size_t)(n0 + r) * 256 + k0 + tx] = __float2bfloat16(tile[tx][r]);
}

// ---------------- CSR build ----------------

__global__ void count_deg_kernel(const int* __restrict__ ei, int* __restrict__ deg) {
    int i = blockIdx.x * blockDim.x + threadIdx.x;
    if (i >= E_TOT) return;
    int dst = (i < N_EDGES) ? ei[N_EDGES + i] : (i - N_EDGES);
    atomicAdd(&deg[dst], 1);
}

__global__ __launch_bounds__(256)
void scan_p1_kernel(const int* __restrict__ deg, int* __restrict__ bsum) {
    const int b = blockIdx.x, t = threadIdx.x;
    const int i = b * 256 + t;
    int v = (i < N_NODES) ? deg[i] : 0;
    #pragma unroll
    for (int off = 1; off < 64; off <<= 1) v += __shfl_xor(v, off, 64);
    __shared__ int ws[4];
    if ((t & 63) == 0) ws[t >> 6] = v;
    __syncthreads();
    if (t == 0) bsum[b] = ws[0] + ws[1] + ws[2] + ws[3];
}

__global__ __launch_bounds__(256)
void scan_p2_kernel(int* __restrict__ bsum) {     // single block; SCAN_NB <= 256
    __shared__ int s[256];
    const int t = threadIdx.x;
    int v = (t < SCAN_NB) ? bsum[t] : 0;
    s[t] = v;
    __syncthreads();
    #pragma unroll
    for (int off = 1; off < 256; off <<= 1) {
        int x = (t >= off) ? s[t - off] : 0;
        __syncthreads();
        s[t] += x;
        __syncthreads();
    }
    if (t < SCAN_NB) bsum[t] = s[t] - v;          // exclusive block offset
}

__global__ __launch_bounds__(256)
void scan_p3_kernel(const int* __restrict__ deg, const int* __restrict__ bsum,
                    int* __restrict__ rowptr) {
    __shared__ int s[256];
    const int b = blockIdx.x, t = threadIdx.x;
    const int i = b * 256 + t;
    int v = (i < N_NODES) ? deg[i] : 0;
    s[t] = v;
    __syncthreads();
    #pragma unroll
    for (int off = 1; off < 256; off <<= 1) {
        int x = (t >= off) ? s[t - off] : 0;
        __syncthreads();
        s[t] += x;
        __syncthreads();
    }
    if (i < N_NODES) rowptr[i] = bsum[b] + s[t] - v;
    if (i == 0) rowptr[N_NODES] = E_TOT;          // total is static
}

__global__ void fill_csr_kernel(const int* __restrict__ ei, const int* __restrict__ rowptr,
                                int* __restrict__ cursor, int* __restrict__ csr_src) {
    int i = blockIdx.x * blockDim.x + threadIdx.x;
    if (i >= E_TOT) return;
    int src, dst;
    if (i < N_EDGES) { src = ei[i]; dst = ei[N_EDGES + i]; }
    else             { src = dst = i - N_EDGES; }
    int pos = atomicAdd(&cursor[dst], 1);
    csr_src[rowptr[dst] + pos] = src;
}

// ---------------- bf16 MFMA GEMM: W-resident-in-LDS, XCD-paired blocks ----------------
// 1D grid 256 (250 active). Pair p = row-group, half h = column half; both halves of a
// pair map to the SAME XCD (b = (p&7) + 16*(p>>3) + 8*h, assuming XCD = b%8 round-robin)
// so the duplicate A-row stream is an L2 hit for the second reader.
// Block = 8 waves (512 thr): stage 64KB W-half into LDS once (XOR-swizzled), B-frags
// into 128 persistent VGPRs, then zero-barrier reg-prefetched A-tile main loop.

template<int CAST>
__global__ __launch_bounds__(512, 2)
void gemm_mfma_kernel(const void* __restrict__ Ain, const __hip_bfloat16* __restrict__ Wt,
                      __hip_bfloat16* __restrict__ C,
                      const float* __restrict__ a_s, const float* __restrict__ a_d,
                      float* __restrict__ asrc, float* __restrict__ adst) {
    __shared__ ushort Wl[128 * 256];    // 64 KB; 16B chunks XOR-swizzled: slot = q ^ (col&7)

    const int b = blockIdx.x;
    const int xcd = b & 7, kslot = b >> 3;
    const int colhalf = kslot & 1;
    const int p = (kslot >> 1) * 8 + xcd;
    if (p >= 125) return;

    const int tid = threadIdx.x;
    const int lane = tid & 63;
    const int l15 = lane & 15, lq = lane >> 4;
    const int w = tid >> 6;
    const int hsel = w >> 2;
    const int stripe = w & 3;
    const int head = colhalf * 2 + hsel;
    const int row_base = p * 320;

    // ---- stage W column-half (128 cols x 256 k) into LDS, swizzled
    {
        const int col = tid >> 2;                 // 0..127
        const char* Wb = (const char*)(Wt + (size_t)(colhalf * 128 + col) * 256);
        #pragma unroll
        for (int j = 0; j < 8; j++) {
            int q = (tid & 3) * 8 + j;            // 16B chunk 0..31
            uint4 v = *reinterpret_cast<const uint4*>(Wb + q * 16);
            *reinterpret_cast<uint4*>(&Wl[col * 256 + ((q ^ (col & 7)) * 8)]) = v;
        }
    }
    __syncthreads();

    // ---- this wave's B fragments -> persistent registers (128 VGPRs)
    bf16x8 bfrag[8][4];
    #pragma unroll
    for (int kt = 0; kt < 8; kt++)
        #pragma unroll
        for (int n = 0; n < 4; n++) {
            int cl = hsel * 64 + n * 16 + l15;
            int q = kt * 4 + lq;
            bfrag[kt][n] = *reinterpret_cast<const bf16x8*>(&Wl[cl * 256 + ((q ^ (cl & 7)) * 8)]);
        }
    __syncthreads();    // frag reads done -> Wl reusable as epilogue strips

    float* strip = reinterpret_cast<float*>(Wl) + w * (16 * 68);   // 4.25KB/wave, wave-private

    float was[4], wad[4];
    #pragma unroll
    for (int n = 0; n < 4; n++) {
        was[n] = a_s[head * 64 + n * 16 + l15];
        wad[n] = a_d[head * 64 + n * 16 + l15];
    }

    auto loadA = [&](int T, bf16x8* a) {
        const int row = row_base + T * 16 + l15;
        if (CAST) {
            const float* Af = (const float*)Ain;
            #pragma unroll
            for (int kt = 0; kt < 8; kt++) {
                float4 u0 = *reinterpret_cast<const float4*>(&Af[(size_t)row * 256 + kt * 32 + lq * 8]);
                float4 u1 = *reinterpret_cast<const float4*>(&Af[(size_t)row * 256 + kt * 32 + lq * 8 + 4]);
                uint4 uv = make_uint4(pk2bf(u0.x, u0.y), pk2bf(u0.z, u0.w),
                                      pk2bf(u1.x, u1.y), pk2bf(u1.z, u1.w));
                a[kt] = *reinterpret_cast<bf16x8*>(&uv);
            }
        } else {
            const __hip_bfloat16* Ab = (const __hip_bfloat16*)Ain;
            #pragma unroll
            for (int kt = 0; kt < 8; kt++) {
                uint4 uv = *reinterpret_cast<const uint4*>(&Ab[(size_t)row * 256 + kt * 32 + lq * 8]);
                a[kt] = *reinterpret_cast<bf16x8*>(&uv);
            }
        }
    };

    bf16x8 aA[8], aB[8];
    loadA(stripe, aA);
    #pragma unroll
    for (int ti = 0; ti < 5; ti++) {
        const int T = stripe + ti * 4;
        if (ti < 4) loadA(T + 4, aB);             // prefetch next tile under the MFMAs
        f32x4 acc[4];
        #pragma unroll
        for (int n = 0; n < 4; n++) acc[n] = (f32x4){0.f, 0.f, 0.f, 0.f};
        #pragma unroll
        for (int kt = 0; kt < 8; kt++)
            #pragma unroll
            for (int n = 0; n < 4; n++)
                acc[n] = __builtin_amdgcn_mfma_f32_16x16x32_bf16(aA[kt], bfrag[kt][n], acc[n], 0, 0, 0);

        // fused alpha dot in fragment layout (cols n*16+l15, reduce over l15)
        #pragma unroll
        for (int reg = 0; reg < 4; reg++) {
            float ps = 0.f, pd = 0.f;
            #pragma unroll
            for (int n = 0; n < 4; n++) {
                float v = acc[n][reg];
                ps = fmaf(v, was[n], ps);
                pd = fmaf(v, wad[n], pd);
            }
            #pragma unroll
            for (int off = 1; off < 16; off <<= 1) {
                ps += __shfl_xor(ps, off, 16);
                pd += __shfl_xor(pd, off, 16);
            }
            const int row = row_base + T * 16 + lq * 4 + reg;
            if (l15 == 0) {
                asrc[row * 4 + head] = ps;
                adst[row * 4 + head] = pd;
            }
        }
        // repack acc through wave-private LDS strip -> coalesced uint4 C stores
        #pragma unroll
        for (int n = 0; n < 4; n++)
            #pragma unroll
            for (int reg = 0; reg < 4; reg++)
                strip[(lq * 4 + reg) * 68 + n * 16 + l15] = acc[n][reg];
        {
            const int r  = lane >> 2;             // output row within 16-row tile
            const int cq = lane & 3;              // 16-col quarter
            f32x4 c0 = *reinterpret_cast<const f32x4*>(&strip[r * 68 + cq * 16]);
            f32x4 c1 = *reinterpret_cast<const f32x4*>(&strip[r * 68 + cq * 16 + 4]);
            f32x4 c2 = *reinterpret_cast<const f32x4*>(&strip[r * 68 + cq * 16 + 8]);
            f32x4 c3 = *reinterpret_cast<const f32x4*>(&strip[r * 68 + cq * 16 + 12]);
            uint4 o0 = make_uint4(pk2bf(c0[0], c0[1]), pk2bf(c0[2], c0[3]),
                                  pk2bf(c1[0], c1[1]), pk2bf(c1[2], c1[3]));
            uint4 o1 = make_uint4(pk2bf(c2[0], c2[1]), pk2bf(c2[2], c2[3]),
                                  pk2bf(c3[0], c3[1]), pk2bf(c3[2], c3[3]));
            const int row = row_base + T * 16 + r;
            __hip_bfloat16* Cp = C + (size_t)row * 256 + head * 64 + cq * 16;
            *reinterpret_cast<uint4*>(Cp) = o0;
            *reinterpret_cast<uint4*>(Cp + 8) = o1;
        }
        #pragma unroll
        for (int kk = 0; kk < 8; kk++) aA[kk] = aB[kk];
    }
}

// ---------------- fused edge-softmax + aggregation (max-free, wave-per-head) ----------------

#define ACHUNK 256

__global__ __launch_bounds__(256)
void gat_fused_agg(const __hip_bfloat16* __restrict__ h, const float* __restrict__ asrc,
                   const float* __restrict__ adst, const int* __restrict__ rowptr,
                   const int* __restrict__ csr_src, const float* __restrict__ bias,
                   __hip_bfloat16* __restrict__ out, int do_relu) {
    __shared__ int   s_src[ACHUNK];
    __shared__ float s_w[ACHUNK][5];    // pad 4->5: conflict-free phase-0 writes
    __shared__ float s_acc[8][HC];
    __shared__ float s_sum[4];

    const int n = blockIdx.x;
    const int t = threadIdx.x;
    const int lane = t & 63;
    const int wid = t >> 6;         // wave id == head in phase 0
    const int grp = t >> 5;         // phase-1 group (edge parity)
    const int gl  = t & 31;         // lane in group; channels gl*8..gl*8+7
    const int h3  = gl >> 3;        // head owning those channels
    const int start = rowptr[n];
    const int deg = rowptr[n + 1] - start;
    const float ad = adst[n * 4 + wid];

    float ssum = 0.f;
    float acc[8] = {0.f, 0.f, 0.f, 0.f, 0.f, 0.f, 0.f, 0.f};

    for (int c0 = 0; c0 < deg; c0 += ACHUNK) {
        const int cn = min(ACHUNK, deg - c0);
        if (c0) __syncthreads();
        for (int e = lane; e < cn; e += 64) {
            int src = csr_src[start + c0 + e];
            if (wid == 0) s_src[e] = src;
            float sc = asrc[src * 4 + wid] + ad;
            sc = (sc >= 0.f) ? sc : 0.2f * sc;   // leaky relu 0.2
            float w = __expf(sc);
            s_w[e][wid] = w;
            ssum += w;
        }
        __syncthreads();
        #pragma unroll 2
        for (int e = grp; e < cn; e += 8) {
            float w = s_w[e][h3];
            uint4 v = *reinterpret_cast<const uint4*>(&h[(size_t)s_src[e] * HC + gl * 8]);
            acc[0] = fmaf(w, bflo(v.x), acc[0]);
            acc[1] = fmaf(w, bfhi(v.x), acc[1]);
            acc[2] = fmaf(w, bflo(v.y), acc[2]);
            acc[3] = fmaf(w, bfhi(v.y), acc[3]);
            acc[4] = fmaf(w, bflo(v.z), acc[4]);
            acc[5] = fmaf(w, bfhi(v.z), acc[5]);
            acc[6] = fmaf(w, bflo(v.w), acc[6]);
            acc[7] = fmaf(w, bfhi(v.w), acc[7]);
        }
    }
    #pragma unroll
    for (int off = 1; off < 64; off <<= 1) ssum += __shfl_xor(ssum, off, 64);
    if (lane == 0) s_sum[wid] = ssum;
    *reinterpret_cast<float4*>(&s_acc[grp][gl * 8])     = make_float4(acc[0], acc[1], acc[2], acc[3]);
    *reinterpret_cast<float4*>(&s_acc[grp][gl * 8 + 4]) = make_float4(acc[4], acc[5], acc[6], acc[7]);
    __syncthreads();
    float tot = 0.f;
    #pragma unroll
    for (int g = 0; g < 8; g++) tot += s_acc[g][t];
    float r = tot / s_sum[t >> 6] + bias[t];
    if (do_relu) r = fmaxf(r, 0.f);
    out[(size_t)n * HC + t] = __float2bfloat16(r);
}

// ---------------- fused pool + MLP layer 1 (one block per graph) ----------------

__global__ __launch_bounds__(1024)
void pool_mlp1_kernel(const __hip_bfloat16* __restrict__ h, const int* __restrict__ batch,
                      const float* __restrict__ Wm1, const float* __restrict__ bm1,
                      float* __restrict__ hidden) {
    __shared__ float s_part[4][256];
    __shared__ float row[256];
    const int g = blockIdx.x, t = threadIdx.x;
    int lo = 0, hi = N_NODES;
    while (lo < hi) { int mid = (lo + hi) >> 1; if (batch[mid] < g) lo = mid + 1; else hi = mid; }
    const int start = lo;
    lo = 0; hi = N_NODES;
    while (lo < hi) { int mid = (lo + hi) >> 1; if (batch[mid] < g + 1) lo = mid + 1; else hi = mid; }
    const int end = lo;

    const int sub = t >> 8, ch = t & 255;
    float a = 0.f;
    for (int n = start + sub; n < end; n += 4)
        a += __bfloat162float(h[(size_t)n * HC + ch]);
    s_part[sub][ch] = a;
    __syncthreads();
    if (t < 256) {
        float c = (float)max(end - start, 1);
        row[t] = (s_part[0][t] + s_part[1][t] + s_part[2][t] + s_part[3][t]) / c;
    }
    __syncthreads();
    float acc = bm1[t];
    for (int k = 0; k < 256; k++) acc = fmaf(row[k], Wm1[(size_t)k * NHID + t], acc);
    hidden[(size_t)g * NHID + t] = fmaxf(acc, 0.f);
}

// ---------------- split-K MLP layer 2 ----------------

__global__ __launch_bounds__(768)
void mlp2_partial(const float* __restrict__ hidden, const float* __restrict__ W,
                  float* __restrict__ partial) {
    __shared__ float row[128];
    const int g = blockIdx.x, ks = blockIdx.y, t = threadIdx.x;
    if (t < 128) row[t] = hidden[(size_t)g * NHID + ks * 128 + t];
    __syncthreads();
    float acc = 0.f;
    const float* Wp = W + (size_t)(ks * 128) * NOUT + t;
    #pragma unroll 4
    for (int k = 0; k < 128; k++) acc = fmaf(row[k], Wp[(size_t)k * NOUT], acc);
    partial[((size_t)ks * N_GRAPH + g) * NOUT + t] = acc;
}

__global__ __launch_bounds__(768)
void mlp2_reduce(const float* __restrict__ partial, const float* __restrict__ b,
                 float* __restrict__ out) {
    const int g = blockIdx.x, t = threadIdx.x;
    float acc = b[t];
    #pragma unroll
    for (int ks = 0; ks < 8; ks++)
        acc += partial[((size_t)ks * N_GRAPH + g) * NOUT + t];
    out[(size_t)g * NOUT + t] = acc;
}

// ---------------- launch ----------------

extern "C" void kernel_launch(void* const* d_in, const int* in_sizes, int n_in,
                              void* d_out, int out_size, void* d_ws, size_t ws_size,
                              hipStream_t stream) {
    const float* x  = (const float*)d_in[0];
    const int* ei   = (const int*)d_in[1];
    const int* batch = (const int*)d_in[2];
    const float* W1 = (const float*)d_in[3];
    const float* as1 = (const float*)d_in[4];
    const float* ad1 = (const float*)d_in[5];
    const float* b1 = (const float*)d_in[6];
    const float* W2 = (const float*)d_in[7];
    const float* as2 = (const float*)d_in[8];
    const float* ad2 = (const float*)d_in[9];
    const float* b2 = (const float*)d_in[10];
    const float* W3 = (const float*)d_in[11];
    const float* as3 = (const float*)d_in[12];
    const float* ad3 = (const float*)d_in[13];
    const float* b3 = (const float*)d_in[14];
    const float* Wm1 = (const float*)d_in[15];
    const float* bm1 = (const float*)d_in[16];
    const float* Wm2 = (const float*)d_in[17];
    const float* bm2 = (const float*)d_in[18];
    float* out = (float*)d_out;

    char* base = (char*)d_ws;
    size_t off = 0;
    auto alloc = [&](size_t bytes) { char* p = base + off; off = (off + bytes + 255) & ~(size_t)255; return p; };
    __hip_bfloat16* hA   = (__hip_bfloat16*)alloc((size_t)N_NODES * 256 * 2);
    __hip_bfloat16* hB   = (__hip_bfloat16*)alloc((size_t)N_NODES * 256 * 2);
    __hip_bfloat16* Wt1  = (__hip_bfloat16*)alloc((size_t)256 * 256 * 2);
    __hip_bfloat16* Wt2  = (__hip_bfloat16*)alloc((size_t)256 * 256 * 2);
    __hip_bfloat16* Wt3  = (__hip_bfloat16*)alloc((size_t)256 * 256 * 2);
    float* asrc   = (float*)alloc((size_t)N_NODES * 4 * 4);
    float* adst   = (float*)alloc((size_t)N_NODES * 4 * 4);
    int*   deg    = (int*)alloc((size_t)N_NODES * 4);      // adjacent to cursor:
    int*   cursor = (int*)alloc((size_t)N_NODES * 4);      // single memset covers both
    int*   rowptr = (int*)alloc((size_t)(N_NODES + 1) * 4);
    int*   bsum   = (int*)alloc((size_t)SCAN_NB * 4);
    int*   csrsrc = (int*)alloc((size_t)E_TOT * 4);
    float* hidden = (float*)alloc((size_t)N_GRAPH * NHID * 4);
    float* part2  = (float*)alloc((size_t)8 * N_GRAPH * NOUT * 4);
    (void)ws_size; (void)n_in; (void)in_sizes; (void)out_size;

    hipMemsetAsync(deg, 0, (size_t)N_NODES * 4 * 2, stream);   // deg + cursor

    conv_wt3_kernel<<<dim3(4, 4, 3), 256, 0, stream>>>(W1, W2, W3, Wt1, Wt2, Wt3);

    // CSR (multi-block scan)
    const int eb = (E_TOT + 255) / 256;
    count_deg_kernel<<<eb, 256, 0, stream>>>(ei, deg);
    scan_p1_kernel<<<SCAN_NB, 256, 0, stream>>>(deg, bsum);
    scan_p2_kernel<<<1, 256, 0, stream>>>(bsum);
    scan_p3_kernel<<<SCAN_NB, 256, 0, stream>>>(deg, bsum, rowptr);
    fill_csr_kernel<<<eb, 256, 0, stream>>>(ei, rowptr, cursor, csrsrc);

    const int ggrid = 256;   // XCD-paired 1D grid; 250 active blocks (125 pairs x 2 halves)

    // layer 1 (A = x, fp32, cast fused into A-tile loads)
    gemm_mfma_kernel<1><<<ggrid, 512, 0, stream>>>(x, Wt1, hA, as1, ad1, asrc, adst);
    gat_fused_agg<<<N_NODES, 256, 0, stream>>>(hA, asrc, adst, rowptr, csrsrc, b1, hB, 1);
    // layer 2
    gemm_mfma_kernel<0><<<ggrid, 512, 0, stream>>>(hB, Wt2, hA, as2, ad2, asrc, adst);
    gat_fused_agg<<<N_NODES, 256, 0, stream>>>(hA, asrc, adst, rowptr, csrsrc, b2, hB, 1);
    // layer 3
    gemm_mfma_kernel<0><<<ggrid, 512, 0, stream>>>(hB, Wt3, hA, as3, ad3, asrc, adst);
    gat_fused_agg<<<N_NODES, 256, 0, stream>>>(hA, asrc, adst, rowptr, csrsrc, b3, hB, 0);

    // fused pool+mlp1, then split-K mlp2
    pool_mlp1_kernel<<<N_GRAPH, 1024, 0, stream>>>(hB, batch, Wm1, bm1, hidden);
    mlp2_partial<<<dim3(N_GRAPH, 8), 768, 0, stream>>>(hidden, Wm2, part2);
    mlp2_reduce<<<N_GRAPH, 768, 0, stream>>>(part2, bm2, out);
}